// Round 10
// baseline (36.220 us; speedup 1.0000x reference)
//
#include <hip/hip_runtime.h>

// CumulativeFlattenedLinear: per-64-timestep-window projection (C=16 -> O=16,
// per-s weight slice, first ND=16 slots zero) + causal cumsum in window + bias.
//
// v10: weights-once + ONE barrier + free-running waves.
//  R9 counters: VALUBusy 42% (17us) vs ~5us useful FMA+scan; weight reloads =
//  4 loads/output element in v5/v9; v6 amortized them but added 16 barriers
//  per 8-wave block (convoy). This kernel has both fixes simultaneously:
//  - 512-thr block, 16 windows (1024 t), 64 KiB LDS staged UP FRONT with
//    high MLP (2 batches of 16 loads/thread), then ONE __syncthreads, then
//    NO further barriers: each wave free-runs 16 window-tasks.
//  - wave owns o-pair (wid, wid+8): w0p[16]+w1p[16] = 32 long-lived regs
//    (proven-resident scale), loaded ONCE per block = 1 weight load/output.
//  - LDS: proven granule-major swizzled tiles [tile:4][c4:4][t:256][slot:4],
//    slot = (c&3)^((t>>3)&3); ds_read_b128 statically indexed, 0 conflicts
//    (R9-measured); element perm absorbed into weight load order (perm =
//    (lane>>3)&3, window-independent).
//  - per window-task: 4 ds_read_b128 + 32 FMA + 12 DPP (wave scan) + 2
//    coalesced dword stores. 2 blocks/CU (64KB LDS), 16 waves/CU.

#define CC 16
#define TT 131072
#define OO 16
#define NK 48
#define ND 16
#define GG 2048
#define NWIN 16          // windows per block
#define NTILE 4          // 256-t tiles per block

// 64-lane inclusive prefix sum via DPP (verified R1).
#define SCAN_STEP(CTRL, RMASK)                                                  \
  {                                                                             \
    int t_ = __builtin_amdgcn_update_dpp(0, __float_as_int(v), (CTRL), (RMASK), \
                                         0xf, true);                            \
    v += __int_as_float(t_);                                                    \
  }

__device__ __forceinline__ float wave_scan64(float v) {
  SCAN_STEP(0x111, 0xf)  // row_shr:1
  SCAN_STEP(0x112, 0xf)  // row_shr:2
  SCAN_STEP(0x114, 0xf)  // row_shr:4
  SCAN_STEP(0x118, 0xf)  // row_shr:8
  SCAN_STEP(0x142, 0xa)  // row_bcast15
  SCAN_STEP(0x143, 0xc)  // row_bcast31
  return v;
}

__global__ __launch_bounds__(512, 4) void cfl_kernel(
    const float* __restrict__ x, const float* __restrict__ weight,
    const float* __restrict__ bias, float* __restrict__ out) {
  // [tile:4][c4:4][t:256][slot:4] floats = 64 KiB, slot = (c&3)^((t>>3)&3)
  __shared__ __attribute__((aligned(16))) float xt[NTILE * 4 * 256 * 4];

  const int tid = threadIdx.x;
  const int lane = tid & 63;
  const int wid = tid >> 6;            // 0..7 -> o-pair (wid, wid+8)

  const int blk = blockIdx.x;          // 1024 blocks; 128 per b-row (no straddle)
  const int b = blk >> 7;
  const int t00 = (blk & 127) * (NWIN * 64);

  const float* xb = x + (size_t)b * CC * TT + t00;

  // ---- stage 64 KiB: 32 dword loads/thread in 2 high-MLP batches ----
#pragma unroll
  for (int batch = 0; batch < 2; ++batch) {
    float xs[16];
#pragma unroll
    for (int i = 0; i < 16; ++i) {
      const int c = batch * 8 + (i >> 1);
      const int sub = i & 1;
      xs[i] = xb[(size_t)c * TT + sub * 512 + tid];
    }
#pragma unroll
    for (int i = 0; i < 16; ++i) asm volatile("" : "+v"(xs[i]));
#pragma unroll
    for (int i = 0; i < 16; ++i) {
      const int c = batch * 8 + (i >> 1);
      const int t = (i & 1) * 512 + tid;     // 0..1023
      const int tt = t >> 8;
      const int tl = t & 255;
      const int slot = (c & 3) ^ ((tl >> 3) & 3);
      xt[(((tt * 4 + (c >> 2)) * 256 + tl) << 2) + slot] = xs[i];
    }
  }

  // ---- weights ONCE per block: o-pair slice in slot order, 32 resident regs
  const int o0 = wid, o1 = wid + 8;
  const int perm = (lane >> 3) & 3;    // window-independent (64 ≡ 0 mod 32)
  float w0p[CC], w1p[CC];
#pragma unroll
  for (int c4 = 0; c4 < 4; ++c4) {
#pragma unroll
    for (int j = 0; j < 4; ++j) {
      const int ce = c4 * 4 + (j ^ perm);
      float a = 0.f, bq = 0.f;
      if (lane >= ND) {
        a = weight[o0 * (CC * NK) + ce * NK + (lane - ND)];
        bq = weight[o1 * (CC * NK) + ce * NK + (lane - ND)];
      }
      asm volatile("" : "+v"(a), "+v"(bq));
      w0p[c4 * 4 + j] = a;
      w1p[c4 * 4 + j] = bq;
    }
  }
  const float b0 = bias[o0];
  const float b1 = bias[o1];

  __syncthreads();  // the ONLY barrier

  float* ob = out + (size_t)b * OO * TT + t00;

#pragma unroll
  for (int win = 0; win < NWIN; ++win) {
    const int tt = win >> 2;
    const int t = (win & 3) * 64 + lane;   // 0..255 within tile
    const float4 xq0 = *(const float4*)&xt[(((tt * 4 + 0) * 256 + t) << 2)];
    const float4 xq1 = *(const float4*)&xt[(((tt * 4 + 1) * 256 + t) << 2)];
    const float4 xq2 = *(const float4*)&xt[(((tt * 4 + 2) * 256 + t) << 2)];
    const float4 xq3 = *(const float4*)&xt[(((tt * 4 + 3) * 256 + t) << 2)];

    float p0 = 0.f, p1 = 0.f;
    p0 = fmaf(xq0.x, w0p[0], p0);  p1 = fmaf(xq0.x, w1p[0], p1);
    p0 = fmaf(xq0.y, w0p[1], p0);  p1 = fmaf(xq0.y, w1p[1], p1);
    p0 = fmaf(xq0.z, w0p[2], p0);  p1 = fmaf(xq0.z, w1p[2], p1);
    p0 = fmaf(xq0.w, w0p[3], p0);  p1 = fmaf(xq0.w, w1p[3], p1);
    p0 = fmaf(xq1.x, w0p[4], p0);  p1 = fmaf(xq1.x, w1p[4], p1);
    p0 = fmaf(xq1.y, w0p[5], p0);  p1 = fmaf(xq1.y, w1p[5], p1);
    p0 = fmaf(xq1.z, w0p[6], p0);  p1 = fmaf(xq1.z, w1p[6], p1);
    p0 = fmaf(xq1.w, w0p[7], p0);  p1 = fmaf(xq1.w, w1p[7], p1);
    p0 = fmaf(xq2.x, w0p[8], p0);  p1 = fmaf(xq2.x, w1p[8], p1);
    p0 = fmaf(xq2.y, w0p[9], p0);  p1 = fmaf(xq2.y, w1p[9], p1);
    p0 = fmaf(xq2.z, w0p[10], p0); p1 = fmaf(xq2.z, w1p[10], p1);
    p0 = fmaf(xq2.w, w0p[11], p0); p1 = fmaf(xq2.w, w1p[11], p1);
    p0 = fmaf(xq3.x, w0p[12], p0); p1 = fmaf(xq3.x, w1p[12], p1);
    p0 = fmaf(xq3.y, w0p[13], p0); p1 = fmaf(xq3.y, w1p[13], p1);
    p0 = fmaf(xq3.z, w0p[14], p0); p1 = fmaf(xq3.z, w1p[14], p1);
    p0 = fmaf(xq3.w, w0p[15], p0); p1 = fmaf(xq3.w, w1p[15], p1);

    const float cs0 = wave_scan64(p0) + b0;
    const float cs1 = wave_scan64(p1) + b1;
    ob[(size_t)o0 * TT + win * 64 + lane] = cs0;
    ob[(size_t)o1 * TT + win * 64 + lane] = cs1;
  }
}

extern "C" void kernel_launch(void* const* d_in, const int* in_sizes, int n_in,
                              void* d_out, int out_size, void* d_ws, size_t ws_size,
                              hipStream_t stream) {
  const float* x = (const float*)d_in[0];
  const float* weight = (const float*)d_in[1];
  const float* bias = (const float*)d_in[2];
  float* out = (float*)d_out;

  // 16384 windows / 16 per block = 1024 blocks of 512 threads.
  cfl_kernel<<<1024, 512, 0, stream>>>(x, weight, bias, out);
}